// Round 5
// baseline (378.439 us; speedup 1.0000x reference)
//
#include <hip/hip_runtime.h>

#define N_NODESC 50000
#define N_EDGESC 640000
#define N_GRAPHSC 64
#define HIDC 128
#define LN_EPSF 1e-5f
#define POOL_SPLIT 16
#define NGRID_GB ((N_NODESC + 255) / 256)
#define NGRID64 ((N_NODESC + 63) / 64)
#define PREP_ELEMS (8192 + 49152 + 49152)   // ninWb + cW1b + cW2b
#define WPREP_NB ((PREP_ELEMS + 255) / 256) // 416
// ---- bucketed CSR build ----
#define B1C 200        // bin blocks
#define BCHUNK 3200    // edges per bin block (200*3200 = 640000 exactly)
#define NBUK 98        // ceil(50000/512)
#define WBUK 512       // nodes per bucket (dst>>9)

typedef short bf16x8 __attribute__((ext_vector_type(8)));
typedef float f32x4 __attribute__((ext_vector_type(4)));

// ---------- helpers ----------
static __device__ __forceinline__ unsigned ord_enc(float f) {
  unsigned u = __float_as_uint(f);
  return (u & 0x80000000u) ? ~u : (u | 0x80000000u);
}
static __device__ __forceinline__ float ord_dec(unsigned u) {
  return __uint_as_float((u & 0x80000000u) ? (u ^ 0x80000000u) : ~u);
}
static __device__ __forceinline__ unsigned short f2bf(float x) {
  unsigned u = __float_as_uint(x);
  u += 0x7fffu + ((u >> 16) & 1u);
  return (unsigned short)(u >> 16);
}
static __device__ __forceinline__ float bf2f(unsigned short b) {
  return __uint_as_float(((unsigned)b) << 16);
}

static __device__ __forceinline__ void mlp16(float in0, float in1, float in2,
    const float* __restrict__ W1, const float* __restrict__ b1,
    const float* __restrict__ g, const float* __restrict__ be,
    const float* __restrict__ W2, const float* __restrict__ b2,
    float* __restrict__ out) {
  float h[16];
  float s1 = 0.f, s2 = 0.f;
#pragma unroll
  for (int j = 0; j < 16; ++j) {
    float v = b1[j] + W1[j*3+0]*in0 + W1[j*3+1]*in1 + W1[j*3+2]*in2;
    v = fmaxf(v, 0.f);
    h[j] = v; s1 += v; s2 += v*v;
  }
  float mu = s1 * (1.f/16.f);
  float var = fmaxf(s2 * (1.f/16.f) - mu*mu, 0.f);
  float rs = rsqrtf(var + LN_EPSF);
  float z[16];
#pragma unroll
  for (int j = 0; j < 16; ++j) z[j] = (h[j]-mu)*rs*g[j] + be[j];
#pragma unroll
  for (int j = 0; j < 16; ++j) {
    float v = b2[j];
#pragma unroll
    for (int k = 0; k < 16; ++k) v += W2[j*16+k]*z[k];
    out[j] = v;
  }
}

// ---------- bin_count: per-block bucket histogram (LDS atomics) + gbound + weight prep ----------
__global__ __launch_bounds__(256) void bin_count_kernel(const int* __restrict__ ei,
    int* __restrict__ counts, const int* __restrict__ batch, int* __restrict__ gstart,
    const float* __restrict__ ninW, unsigned short* __restrict__ ninWb,
    const float* __restrict__ cW1, unsigned short* __restrict__ cW1b,
    const float* __restrict__ cW2, unsigned short* __restrict__ cW2b) {
  const int b = blockIdx.x;
  if (b < B1C) {
    __shared__ int cnt[NBUK];
    for (int i = threadIdx.x; i < NBUK; i += 256) cnt[i] = 0;
    __syncthreads();
    const int e0 = b * BCHUNK;
    const int e1 = e0 + BCHUNK;
    for (int e = e0 + threadIdx.x; e < e1; e += 256)
      atomicAdd(&cnt[ei[N_EDGESC + e] >> 9], 1);
    __syncthreads();
    for (int i = threadIdx.x; i < NBUK; i += 256)
      counts[i * B1C + b] = cnt[i];
  } else if (b < B1C + NGRID_GB) {
    int i = (b - B1C) * 256 + threadIdx.x;
    if (i >= N_NODESC) return;
    int bb_ = batch[i];
    int prev = (i == 0) ? -1 : batch[i-1];
    for (int g = prev + 1; g <= bb_; ++g) gstart[g] = i;
    if (i == N_NODESC - 1) {
      for (int g = bb_ + 1; g <= N_GRAPHSC; ++g) gstart[g] = N_NODESC;
    }
  } else {
    int i = (b - B1C - NGRID_GB) * 256 + threadIdx.x;
    if (i < 8192) {
      int f = i >> 6, k = i & 63;
      ninWb[i] = (k < 45) ? f2bf(ninW[f*45 + k]) : (unsigned short)0;
    } else if (i < 8192 + 49152) {
      int j = i - 8192;
      cW1b[j] = f2bf(cW1[j]);
    } else if (i < PREP_ELEMS) {
      int j = i - 8192 - 49152;
      cW2b[j] = f2bf(cW2[j]);
    }
  }
}

// ---------- bin_scanA: per-bucket exclusive scan over the 200 block counts ----------
__global__ __launch_bounds__(256) void bin_scanA_kernel(const int* __restrict__ counts,
                                                        int* __restrict__ offl,
                                                        int* __restrict__ btot) {
  const int buk = blockIdx.x, t = threadIdx.x;
  const int lane = t & 63, w = t >> 6;
  int v = (t < B1C) ? counts[buk * B1C + t] : 0;
  const int orig = v;
#pragma unroll
  for (int off = 1; off < 64; off <<= 1) {
    int n = __shfl_up(v, off);
    if (lane >= off) v += n;
  }
  __shared__ int wsum[4];
  if (lane == 63) wsum[w] = v;
  __syncthreads();
  if (t == 0) {
    int run = 0;
#pragma unroll
    for (int k = 0; k < 4; ++k) { int x = wsum[k]; wsum[k] = run; run += x; }
  }
  __syncthreads();
  int incl = v + wsum[w];
  if (t < B1C) offl[buk * B1C + t] = incl - orig;
  if (t == 255) btot[buk] = incl;
}

// ---------- bin_scanB: scan bucket totals -> bucket bases ----------
__global__ __launch_bounds__(128) void bin_scanB_kernel(const int* __restrict__ btot,
                                                        int* __restrict__ bb) {
  const int t = threadIdx.x, lane = t & 63, w = t >> 6;
  int v = (t < NBUK) ? btot[t] : 0;
  const int orig = v;
#pragma unroll
  for (int off = 1; off < 64; off <<= 1) {
    int n = __shfl_up(v, off);
    if (lane >= off) v += n;
  }
  __shared__ int ws2[2];
  if (lane == 63) ws2[w] = v;
  __syncthreads();
  int add = (w == 1) ? ws2[0] : 0;
  int excl = v + add - orig;
  if (t < NBUK) bb[t] = excl;
  if (t == 0) bb[NBUK] = N_EDGESC;
}

// ---------- bin_write (LDS cursors, partition pairs by bucket) + encoder MFMA blocks ----------
__global__ __launch_bounds__(256, 4) void bin_write_enc_kernel(
    const int* __restrict__ ei, const int* __restrict__ offl, const int* __restrict__ bb,
    int2* __restrict__ pairs,
    const float* __restrict__ x,
    const float* __restrict__ aW1, const float* __restrict__ ab1,
    const float* __restrict__ ag,  const float* __restrict__ abe,
    const float* __restrict__ aW2, const float* __restrict__ ab2,
    const float* __restrict__ oW1, const float* __restrict__ ob1,
    const float* __restrict__ og,  const float* __restrict__ obe,
    const float* __restrict__ oW2, const float* __restrict__ ob2,
    const unsigned short* __restrict__ ninWb, const float* __restrict__ ninb,
    unsigned short* __restrict__ Hb) {
  __shared__ unsigned short Ab[64*136];
  const int t = threadIdx.x;

  if (blockIdx.x < B1C) {
    // ---- partition pass: LDS cursors, no global atomics ----
    int* cur = (int*)Ab;
    const int blk = blockIdx.x;
    for (int i = t; i < NBUK; i += 256) cur[i] = bb[i] + offl[i * B1C + blk];
    __syncthreads();
    const int e0 = blk * BCHUNK;
    const int e1 = e0 + BCHUNK;
    for (int e = e0 + t; e < e1; e += 256) {
      int s = ei[e], d = ei[N_EDGESC + e];
      int pos = atomicAdd(&cur[d >> 9], 1);
      pairs[pos] = make_int2(s, d);
    }
    return;
  }

  // ---- encoder part ----
  const int nb = (blockIdx.x - B1C) * 64;

  if (t < 192) {
    const int n = t & 63;
    const int gn = nb + n;
    const int grp = t >> 6;
    if (gn < N_NODESC) {
      const float* xr = x + gn * 19;
      if (grp == 0) {
        float z[16];
        mlp16(xr[9], xr[10], xr[11], aW1, ab1, ag, abe, aW2, ab2, z);
#pragma unroll
        for (int k = 0; k < 16; ++k) Ab[n*136 + 13 + k] = f2bf(z[k]);
      } else if (grp == 1) {
        float z[16];
        mlp16(xr[12], xr[13], xr[14], oW1, ob1, og, obe, oW2, ob2, z);
#pragma unroll
        for (int k = 0; k < 16; ++k) Ab[n*136 + 29 + k] = f2bf(z[k]);
      } else {
#pragma unroll
        for (int k = 0; k < 9; ++k) Ab[n*136 + k] = f2bf(xr[k]);
#pragma unroll
        for (int k = 0; k < 4; ++k) Ab[n*136 + 9 + k] = f2bf(xr[15 + k]);
#pragma unroll
        for (int k = 45; k < 64; ++k) Ab[n*136 + k] = 0;
      }
    } else {
      if (grp == 0) {
#pragma unroll
        for (int k = 0; k < 16; ++k) Ab[n*136 + 13 + k] = 0;
      } else if (grp == 1) {
#pragma unroll
        for (int k = 0; k < 16; ++k) Ab[n*136 + 29 + k] = 0;
      } else {
#pragma unroll
        for (int k = 0; k < 13; ++k) Ab[n*136 + k] = 0;
#pragma unroll
        for (int k = 45; k < 64; ++k) Ab[n*136 + k] = 0;
      }
    }
  }
  __syncthreads();

  const int lane = t & 63, wv = t >> 6;
  const int quad = lane >> 4, l16 = lane & 15;
  const int arow = (wv*16 + l16)*136 + quad*8;
  f32x4 acc[8];
#pragma unroll
  for (int ft = 0; ft < 8; ++ft) acc[ft] = (f32x4){0.f,0.f,0.f,0.f};
#pragma unroll
  for (int ks = 0; ks < 2; ++ks) {
    bf16x8 a = *(const bf16x8*)(const void*)&Ab[arow + ks*32];
#pragma unroll
    for (int ft = 0; ft < 8; ++ft) {
      bf16x8 bfr = *(const bf16x8*)&ninWb[(ft*16 + l16)*64 + quad*8 + ks*32];
      acc[ft] = __builtin_amdgcn_mfma_f32_16x16x32_bf16(a, bfr, acc[ft], 0, 0, 0);
    }
  }
  float bbv[8];
#pragma unroll
  for (int ft = 0; ft < 8; ++ft) bbv[ft] = ninb[ft*16 + l16];
  __syncthreads();
#pragma unroll
  for (int r = 0; r < 4; ++r) {
    int nloc = wv*16 + quad*4 + r;
#pragma unroll
    for (int ft = 0; ft < 8; ++ft)
      Ab[nloc*136 + ft*16 + l16] = f2bf(acc[ft][r] + bbv[ft]);
  }
  __syncthreads();
#pragma unroll
  for (int i = 0; i < 4; ++i) {
    int chunk = t + i*256;
    int n = chunk >> 4, c8 = chunk & 15;
    int gn = nb + n;
    if (gn < N_NODESC)
      *(bf16x8*)&Hb[gn*HIDC + c8*8] = *(const bf16x8*)&Ab[n*136 + c8*8];
  }
}

// ---------- bucket_build: per-bucket LDS hist -> scan -> rowptr + esrc scatter (LDS cursors) ----------
__global__ __launch_bounds__(256) void bucket_build_kernel(const int2* __restrict__ pairs,
    const int* __restrict__ bb, int* __restrict__ rowptr, int* __restrict__ esrc) {
  __shared__ int hist[WBUK];
  __shared__ int wsum[4];
  __shared__ int totS;
  const int b = blockIdx.x, t = threadIdx.x;
  const int lane = t & 63, w = t >> 6;
  const int node0 = b * WBUK;
  for (int i = t; i < WBUK; i += 256) hist[i] = 0;
  __syncthreads();
  const int base = bb[b], end = bb[b + 1];
  for (int p = base + t; p < end; p += 256)
    atomicAdd(&hist[pairs[p].y - node0], 1);
  __syncthreads();
  const int v0 = hist[t], v1 = hist[256 + t];
  // exclusive scan of hist[0..255]
  int a = v0;
#pragma unroll
  for (int off = 1; off < 64; off <<= 1) {
    int n = __shfl_up(a, off);
    if (lane >= off) a += n;
  }
  if (lane == 63) wsum[w] = a;
  __syncthreads();
  if (t == 0) {
    int run = 0;
#pragma unroll
    for (int k = 0; k < 4; ++k) { int x = wsum[k]; wsum[k] = run; run += x; }
    totS = run;
  }
  __syncthreads();
  const int e0 = a + wsum[w] - v0;
  const int tot0 = totS;
  __syncthreads();
  // exclusive scan of hist[256..511] (+ carry tot0)
  int c = v1;
#pragma unroll
  for (int off = 1; off < 64; off <<= 1) {
    int n = __shfl_up(c, off);
    if (lane >= off) c += n;
  }
  if (lane == 63) wsum[w] = c;
  __syncthreads();
  if (t == 0) {
    int run = 0;
#pragma unroll
    for (int k = 0; k < 4; ++k) { int x = wsum[k]; wsum[k] = run; run += x; }
  }
  __syncthreads();
  const int e1 = tot0 + c + wsum[w] - v1;
  // write rowptr, convert hist -> cursors
  hist[t] = e0;
  hist[256 + t] = e1;
  const int n0 = node0 + t, n1 = node0 + 256 + t;
  if (n0 < N_NODESC) rowptr[n0] = base + e0;
  if (n1 < N_NODESC) rowptr[n1] = base + e1;
  __syncthreads();
  for (int p = base + t; p < end; p += 256) {
    int2 pr = pairs[p];
    int slot = base + atomicAdd(&hist[pr.y - node0], 1);
    esrc[slot] = pr.x;
  }
  if (b == NBUK - 1 && t == 0) rowptr[N_NODESC] = N_EDGESC;
}

// ---------- fused layer: agg -> GEMM1 -> LN -> GEMM2 -> LN -> +res (-> gate) ----------
// LDS holds ONLY the 64x128 A-tile (17.4 KB): W fragments are read straight from
// global (L2-hot, 64 KB/layer) -> ~5-6 blocks/CU so the latency-bound gather keeps
// Round-2-level TLP while the Mb round-trip and 3 dispatches disappear.
template<bool GATE>
__global__ __launch_bounds__(256, 4) void layer_kernel(
    const unsigned short* __restrict__ Hin,
    const int* __restrict__ rowptr, const int* __restrict__ esrc,
    const float* __restrict__ epsp,
    const unsigned short* __restrict__ W1b, const float* __restrict__ b1,
    const float* __restrict__ g1, const float* __restrict__ be1,
    const unsigned short* __restrict__ W2b, const float* __restrict__ b2,
    const float* __restrict__ lng, const float* __restrict__ lnb,
    unsigned short* __restrict__ Hout,
    const float* __restrict__ gW1, const float* __restrict__ gb1,
    const float* __restrict__ glng, const float* __restrict__ glnb,
    const float* __restrict__ gW2, const float* __restrict__ gb2,
    const int* __restrict__ batch, float* __restrict__ gateb,
    unsigned* __restrict__ gmaxu) {
  __shared__ unsigned short Ab[64*136];   // M tile -> T tile -> OUT tile -> (H tile)
  __shared__ unsigned sgm[N_GRAPHSC];
  const int t = threadIdx.x;
  const int nb = blockIdx.x * 64;
  if (GATE && t < N_GRAPHSC) sgm[t] = 0u;

  // fused aggregation straight into Ab: m = (1+eps)*h + sum_{src} h[src]
  {
    const float e1 = 1.0f + epsp[0];
    const int c8 = t & 15;
    const int nv = t >> 4;
#pragma unroll
    for (int p = 0; p < 4; ++p) {
      const int n = p*16 + nv;
      const int gn = nb + n;
      bf16x8 m8 = {0,0,0,0,0,0,0,0};
      if (gn < N_NODESC) {
        bf16x8 h = *(const bf16x8*)&Hin[gn*HIDC + c8*8];
        float acc[8];
#pragma unroll
        for (int k = 0; k < 8; ++k) acc[k] = 0.f;
        int s = rowptr[gn];
        const int e = rowptr[gn+1];
        for (; s + 8 <= e; s += 8) {
          int i0 = esrc[s],   i1 = esrc[s+1], i2 = esrc[s+2], i3 = esrc[s+3];
          int i4 = esrc[s+4], i5 = esrc[s+5], i6 = esrc[s+6], i7 = esrc[s+7];
          bf16x8 x0 = *(const bf16x8*)&Hin[i0*HIDC + c8*8];
          bf16x8 x1 = *(const bf16x8*)&Hin[i1*HIDC + c8*8];
          bf16x8 x2 = *(const bf16x8*)&Hin[i2*HIDC + c8*8];
          bf16x8 x3 = *(const bf16x8*)&Hin[i3*HIDC + c8*8];
          bf16x8 x4 = *(const bf16x8*)&Hin[i4*HIDC + c8*8];
          bf16x8 x5 = *(const bf16x8*)&Hin[i5*HIDC + c8*8];
          bf16x8 x6 = *(const bf16x8*)&Hin[i6*HIDC + c8*8];
          bf16x8 x7 = *(const bf16x8*)&Hin[i7*HIDC + c8*8];
#pragma unroll
          for (int k = 0; k < 8; ++k)
            acc[k] += ((bf2f((unsigned short)x0[k]) + bf2f((unsigned short)x1[k]))
                     + (bf2f((unsigned short)x2[k]) + bf2f((unsigned short)x3[k])))
                    + ((bf2f((unsigned short)x4[k]) + bf2f((unsigned short)x5[k]))
                     + (bf2f((unsigned short)x6[k]) + bf2f((unsigned short)x7[k])));
        }
        for (; s + 4 <= e; s += 4) {
          int i0 = esrc[s], i1 = esrc[s+1], i2 = esrc[s+2], i3 = esrc[s+3];
          bf16x8 x0 = *(const bf16x8*)&Hin[i0*HIDC + c8*8];
          bf16x8 x1 = *(const bf16x8*)&Hin[i1*HIDC + c8*8];
          bf16x8 x2 = *(const bf16x8*)&Hin[i2*HIDC + c8*8];
          bf16x8 x3 = *(const bf16x8*)&Hin[i3*HIDC + c8*8];
#pragma unroll
          for (int k = 0; k < 8; ++k)
            acc[k] += (bf2f((unsigned short)x0[k]) + bf2f((unsigned short)x1[k]))
                    + (bf2f((unsigned short)x2[k]) + bf2f((unsigned short)x3[k]));
        }
        for (; s < e; ++s) {
          bf16x8 x0 = *(const bf16x8*)&Hin[esrc[s]*HIDC + c8*8];
#pragma unroll
          for (int k = 0; k < 8; ++k) acc[k] += bf2f((unsigned short)x0[k]);
        }
#pragma unroll
        for (int k = 0; k < 8; ++k)
          m8[k] = (short)f2bf(e1*bf2f((unsigned short)h[k]) + acc[k]);
      }
      *(bf16x8*)&Ab[n*136 + c8*8] = m8;
    }
  }
  __syncthreads();

  const int lane = t & 63, wv = t >> 6;
  const int quad = lane >> 4, l16 = lane & 15;
  const int arow = (wv*16 + l16)*136 + quad*8;

  // MFMA loop 1 (B fragments straight from global W1b)
  f32x4 acc[8];
#pragma unroll
  for (int ft = 0; ft < 8; ++ft) acc[ft] = (f32x4){0.f,0.f,0.f,0.f};
#pragma unroll
  for (int ks = 0; ks < 4; ++ks) {
    bf16x8 a = *(const bf16x8*)(const void*)&Ab[arow + ks*32];
    bf16x8 wfr[8];
#pragma unroll
    for (int ft = 0; ft < 8; ++ft)
      wfr[ft] = *(const bf16x8*)&W1b[(ft*16 + l16)*HIDC + quad*8 + ks*32];
#pragma unroll
    for (int ft = 0; ft < 8; ++ft)
      acc[ft] = __builtin_amdgcn_mfma_f32_16x16x32_bf16(a, wfr[ft], acc[ft], 0, 0, 0);
  }

  // epilogue 1: bias + relu + LN -> T in Ab
  {
    float bbv[8], gg[8], bee[8];
#pragma unroll
    for (int ft = 0; ft < 8; ++ft) {
      int f = ft*16 + l16;
      bbv[ft] = b1[f]; gg[ft] = g1[f]; bee[ft] = be1[f];
    }
    float s1[4] = {0,0,0,0}, s2[4] = {0,0,0,0};
#pragma unroll
    for (int ft = 0; ft < 8; ++ft)
#pragma unroll
      for (int r = 0; r < 4; ++r) {
        float v = fmaxf(acc[ft][r] + bbv[ft], 0.f);
        acc[ft][r] = v; s1[r] += v; s2[r] += v*v;
      }
#pragma unroll
    for (int m = 1; m < 16; m <<= 1)
#pragma unroll
      for (int r = 0; r < 4; ++r) {
        s1[r] += __shfl_xor(s1[r], m);
        s2[r] += __shfl_xor(s2[r], m);
      }
    float mu[4], rs[4];
#pragma unroll
    for (int r = 0; r < 4; ++r) {
      mu[r] = s1[r] * (1.f/128.f);
      float var = fmaxf(s2[r] * (1.f/128.f) - mu[r]*mu[r], 0.f);
      rs[r] = rsqrtf(var + LN_EPSF);
    }
    __syncthreads();
#pragma unroll
    for (int r = 0; r < 4; ++r) {
      int nloc = wv*16 + quad*4 + r;
#pragma unroll
      for (int ft = 0; ft < 8; ++ft) {
        float o = (acc[ft][r] - mu[r])*rs[r]*gg[ft] + bee[ft];
        Ab[nloc*136 + ft*16 + l16] = f2bf(o);
      }
    }
  }
  __syncthreads();

  // MFMA loop 2 (B from global W2b)
#pragma unroll
  for (int ft = 0; ft < 8; ++ft) acc[ft] = (f32x4){0.f,0.f,0.f,0.f};
#pragma unroll
  for (int ks = 0; ks < 4; ++ks) {
    bf16x8 a = *(const bf16x8*)(const void*)&Ab[arow + ks*32];
    bf16x8 wfr[8];
#pragma unroll
    for (int ft = 0; ft < 8; ++ft)
      wfr[ft] = *(const bf16x8*)&W2b[(ft*16 + l16)*HIDC + quad*8 + ks*32];
#pragma unroll
    for (int ft = 0; ft < 8; ++ft)
      acc[ft] = __builtin_amdgcn_mfma_f32_16x16x32_bf16(a, wfr[ft], acc[ft], 0, 0, 0);
  }

  // epilogue 2: bias + relu + LN -> Ab
  {
    float bbv[8], gg[8], bee[8];
#pragma unroll
    for (int ft = 0; ft < 8; ++ft) {
      int f = ft*16 + l16;
      bbv[ft] = b2[f]; gg[ft] = lng[f]; bee[ft] = lnb[f];
    }
    float s1[4] = {0,0,0,0}, s2[4] = {0,0,0,0};
#pragma unroll
    for (int ft = 0; ft < 8; ++ft)
#pragma unroll
      for (int r = 0; r < 4; ++r) {
        float v = fmaxf(acc[ft][r] + bbv[ft], 0.f);
        acc[ft][r] = v; s1[r] += v; s2[r] += v*v;
      }
#pragma unroll
    for (int m = 1; m < 16; m <<= 1)
#pragma unroll
      for (int r = 0; r < 4; ++r) {
        s1[r] += __shfl_xor(s1[r], m);
        s2[r] += __shfl_xor(s2[r], m);
      }
    float mu[4], rs[4];
#pragma unroll
    for (int r = 0; r < 4; ++r) {
      mu[r] = s1[r] * (1.f/128.f);
      float var = fmaxf(s2[r] * (1.f/128.f) - mu[r]*mu[r], 0.f);
      rs[r] = rsqrtf(var + LN_EPSF);
    }
    __syncthreads();
#pragma unroll
    for (int r = 0; r < 4; ++r) {
      int nloc = wv*16 + quad*4 + r;
#pragma unroll
      for (int ft = 0; ft < 8; ++ft) {
        float o = (acc[ft][r] - mu[r])*rs[r]*gg[ft] + bee[ft];
        Ab[nloc*136 + ft*16 + l16] = f2bf(o);
      }
    }
  }
  __syncthreads();
  // final store: + residual (Hin row), coalesced 16B chunks.
  // When GATE, also keep final H in Ab (same thread owns read+write slot).
#pragma unroll
  for (int i = 0; i < 4; ++i) {
    int chunk = t + i*256;
    int n = chunk >> 4, cc = chunk & 15;
    int gn = nb + n;
    bf16x8 o8 = {0,0,0,0,0,0,0,0};
    if (gn < N_NODESC) {
      bf16x8 vv = *(const bf16x8*)&Ab[n*136 + cc*8];
      bf16x8 rr = *(const bf16x8*)&Hin[gn*HIDC + cc*8];
#pragma unroll
      for (int k = 0; k < 8; ++k)
        o8[k] = (short)f2bf(bf2f((unsigned short)vv[k]) + bf2f((unsigned short)rr[k]));
      *(bf16x8*)&Hout[gn*HIDC + cc*8] = o8;
    }
    if (GATE) *(bf16x8*)&Ab[n*136 + cc*8] = o8;
  }

  if (GATE) {
    __syncthreads();   // Ab now holds final H for all threads

    // gate MFMA: B fragments from gW1 (f32), converted in-register to bf16
    f32x4 gacc[4];
#pragma unroll
    for (int ft = 0; ft < 4; ++ft) gacc[ft] = (f32x4){0.f,0.f,0.f,0.f};
#pragma unroll
    for (int ks = 0; ks < 4; ++ks) {
      bf16x8 a = *(const bf16x8*)(const void*)&Ab[arow + ks*32];
#pragma unroll
      for (int ft = 0; ft < 4; ++ft) {
        const float* wp = &gW1[(ft*16 + l16)*HIDC + quad*8 + ks*32];
        float4 w0 = *(const float4*)wp;
        float4 w1 = *(const float4*)(wp + 4);
        bf16x8 wb;
        wb[0] = (short)f2bf(w0.x); wb[1] = (short)f2bf(w0.y);
        wb[2] = (short)f2bf(w0.z); wb[3] = (short)f2bf(w0.w);
        wb[4] = (short)f2bf(w1.x); wb[5] = (short)f2bf(w1.y);
        wb[6] = (short)f2bf(w1.z); wb[7] = (short)f2bf(w1.w);
        gacc[ft] = __builtin_amdgcn_mfma_f32_16x16x32_bf16(a, wb, gacc[ft], 0, 0, 0);
      }
    }

    float bbv[4], gg[4], bee[4], w2v[4];
#pragma unroll
    for (int ft = 0; ft < 4; ++ft) {
      int f = ft*16 + l16;
      bbv[ft] = gb1[f]; gg[ft] = glng[f]; bee[ft] = glnb[f]; w2v[ft] = gW2[f];
    }
    float s1[4] = {0,0,0,0}, s2[4] = {0,0,0,0};
#pragma unroll
    for (int ft = 0; ft < 4; ++ft)
#pragma unroll
      for (int r = 0; r < 4; ++r) {
        float v = fmaxf(gacc[ft][r] + bbv[ft], 0.f);
        gacc[ft][r] = v; s1[r] += v; s2[r] += v*v;
      }
#pragma unroll
    for (int m = 1; m < 16; m <<= 1)
#pragma unroll
      for (int r = 0; r < 4; ++r) {
        s1[r] += __shfl_xor(s1[r], m);
        s2[r] += __shfl_xor(s2[r], m);
      }
    float pd[4];
#pragma unroll
    for (int r = 0; r < 4; ++r) {
      float mu = s1[r] * (1.f/64.f);
      float var = fmaxf(s2[r] * (1.f/64.f) - mu*mu, 0.f);
      float rs = rsqrtf(var + LN_EPSF);
      float p = 0.f;
#pragma unroll
      for (int ft = 0; ft < 4; ++ft)
        p += ((gacc[ft][r] - mu)*rs*gg[ft] + bee[ft]) * w2v[ft];
      pd[r] = p;
    }
#pragma unroll
    for (int m = 1; m < 16; m <<= 1)
#pragma unroll
      for (int r = 0; r < 4; ++r) pd[r] += __shfl_xor(pd[r], m);
    if (l16 == 0) {
      float b2v = gb2[0];
#pragma unroll
      for (int r = 0; r < 4; ++r) {
        int node = nb + wv*16 + quad*4 + r;
        if (node < N_NODESC) {
          float gv = pd[r] + b2v;
          gateb[node] = gv;
          atomicMax(&sgm[batch[node]], ord_enc(gv));
        }
      }
    }
    __syncthreads();
    if (t < N_GRAPHSC && sgm[t] != 0u) atomicMax(&gmaxu[t], sgm[t]);
  }
}

// ---------- segmented softmax-weighted pooling (bf16 H) ----------
__global__ __launch_bounds__(256) void pool_kernel(const unsigned short* __restrict__ Hb,
    const float* __restrict__ gateb, const int* __restrict__ gstart,
    const unsigned* __restrict__ gmaxu, float* __restrict__ S,
    float* __restrict__ denom) {
  const int g    = blockIdx.x / POOL_SPLIT;
  const int part = blockIdx.x % POOL_SPLIT;
  const int s0 = gstart[g], s1 = gstart[g+1];
  const int cnt = s1 - s0;
  const int chunk = (cnt + POOL_SPLIT - 1) / POOL_SPLIT;
  int lo = s0 + part * chunk;
  int hi = lo + chunk; if (hi > s1) hi = s1;
  const int t = threadIdx.x;
  const int c8 = t & 15;
  const int v  = t >> 4;
  const float gm = ord_dec(gmaxu[g]);
  float acc[8];
#pragma unroll
  for (int k = 0; k < 8; ++k) acc[k] = 0.f;
  float de = 0.f;
  for (int n = lo + v; n < hi; n += 16) {
    float e = expf(gateb[n] - gm);
    bf16x8 hv = *(const bf16x8*)&Hb[n*HIDC + c8*8];
#pragma unroll
    for (int k = 0; k < 8; ++k) acc[k] += e * bf2f((unsigned short)hv[k]);
    if (c8 == 0) de += e;
  }
  __shared__ float sacc[16*128];
  __shared__ float sden[16];
#pragma unroll
  for (int k = 0; k < 8; ++k) sacc[v*128 + c8*8 + k] = acc[k];
  if (c8 == 0) sden[v] = de;
  __syncthreads();
  if (t < 128) {
    float s = 0.f;
#pragma unroll
    for (int vv = 0; vv < 16; ++vv) s += sacc[vv*128 + t];
    atomicAdd(&S[g*HIDC + t], s);
  }
  if (t == 0) {
    float d = 0.f;
#pragma unroll
    for (int vv = 0; vv < 16; ++vv) d += sden[vv];
    atomicAdd(&denom[g], d);
  }
}

// ---------- head MLP per graph ----------
__global__ __launch_bounds__(64) void head_kernel(const float* __restrict__ S,
    const float* __restrict__ denom, const float* __restrict__ W1,
    const float* __restrict__ b1, const float* __restrict__ g,
    const float* __restrict__ be, const float* __restrict__ W2,
    const float* __restrict__ b2, float* __restrict__ out) {
  const int gr = blockIdx.x;
  const int j = threadIdx.x;
  const float inv = 1.0f / denom[gr];
  float v = b1[j];
  for (int k = 0; k < HIDC; ++k) v += (S[gr*HIDC + k] * inv) * W1[j*HIDC + k];
  v = fmaxf(v, 0.f);
  float s1 = v, s2 = v*v;
  for (int off = 32; off; off >>= 1) { s1 += __shfl_xor(s1, off); s2 += __shfl_xor(s2, off); }
  float mu = s1 * (1.f/64.f);
  float var = fmaxf(s2 * (1.f/64.f) - mu*mu, 0.f);
  float rs = rsqrtf(var + LN_EPSF);
  float z = (v-mu)*rs*g[j] + be[j];
  float p = z * W2[j];
  for (int off = 32; off; off >>= 1) p += __shfl_xor(p, off);
  if (j == 0) out[gr] = p + b2[0];
}

// ---------- launch ----------
extern "C" void kernel_launch(void* const* d_in, const int* in_sizes, int n_in,
                              void* d_out, int out_size, void* d_ws, size_t ws_size,
                              hipStream_t stream) {
  (void)in_sizes; (void)n_in; (void)out_size; (void)ws_size;
  const float* x     = (const float*)d_in[0];
  const int*   ei    = (const int*)d_in[1];
  const int*   batch = (const int*)d_in[2];
  const float* aW1 = (const float*)d_in[3];
  const float* ab1 = (const float*)d_in[4];
  const float* ag  = (const float*)d_in[5];
  const float* abe = (const float*)d_in[6];
  const float* aW2 = (const float*)d_in[7];
  const float* ab2 = (const float*)d_in[8];
  const float* oW1 = (const float*)d_in[9];
  const float* ob1 = (const float*)d_in[10];
  const float* og  = (const float*)d_in[11];
  const float* obe = (const float*)d_in[12];
  const float* oW2 = (const float*)d_in[13];
  const float* ob2 = (const float*)d_in[14];
  const float* ninW = (const float*)d_in[15];
  const float* ninb = (const float*)d_in[16];
  const float* cW1 = (const float*)d_in[17];
  const float* cb1 = (const float*)d_in[18];
  const float* cg  = (const float*)d_in[19];
  const float* cbe = (const float*)d_in[20];
  const float* cW2 = (const float*)d_in[21];
  const float* cb2 = (const float*)d_in[22];
  const float* eps = (const float*)d_in[23];
  const float* lng = (const float*)d_in[24];
  const float* lnb = (const float*)d_in[25];
  const float* gW1 = (const float*)d_in[26];
  const float* gb1 = (const float*)d_in[27];
  const float* gg  = (const float*)d_in[28];
  const float* gbe = (const float*)d_in[29];
  const float* gW2 = (const float*)d_in[30];
  const float* gb2 = (const float*)d_in[31];
  const float* hW1 = (const float*)d_in[32];
  const float* hb1 = (const float*)d_in[33];
  const float* hg  = (const float*)d_in[34];
  const float* hbe = (const float*)d_in[35];
  const float* hW2 = (const float*)d_in[36];
  const float* hb2 = (const float*)d_in[37];

  char* ws = (char*)d_ws;
  unsigned short* Ha = (unsigned short*)(ws + 0);          // 12,800,000 B
  unsigned short* Hc = (unsigned short*)(ws + 12800000);   // 12,800,000 B
  // CSR-build scratch (region formerly Mb; Mb eliminated by fusion):
  int2* pairs  = (int2*)(ws + 25600000);                   // 640000*8 = 5,120,000 B
  int* counts  = (int*)(ws + 30720000);                    // 98*200*4 = 78,400 B
  int* offl    = (int*)(ws + 30800000);                    // 78,400 B
  int* btot    = (int*)(ws + 30880000);                    // 392 B
  int* bb      = (int*)(ws + 30881024);                    // 99*4 = 396 B
  float* gateb = (float*)(ws + 38400000);                  // 200,000 B
  // --- contiguous zero region: S | denom | gmaxu ---
  float* S     = (float*)(ws + 38800000);                  // 32,768 B
  float* denom = (float*)(ws + 38832768);                  // 256 B
  unsigned* gmaxu = (unsigned*)(ws + 38833024);            // 256 B
  // -------------------------------------------------------
  int* rowptr  = (int*)(ws + 38833280);                    // 200,004 B
  int* esrc    = (int*)(ws + 39233284);                    // 2,560,000 B
  int* gstart  = (int*)(ws + 41793540);                    // 260 B
  unsigned short* ninWb = (unsigned short*)(ws + 41800000);// 16,384 B
  unsigned short* cW1b  = (unsigned short*)(ws + 41816384);// 98,304 B
  unsigned short* cW2b  = (unsigned short*)(ws + 41914688);// 98,304 B

  hipMemsetAsync(S, 0, 33280, stream);         // S + denom + gmaxu

  bin_count_kernel<<<B1C + NGRID_GB + WPREP_NB, 256, 0, stream>>>(
      ei, counts, batch, gstart, ninW, ninWb, cW1, cW1b, cW2, cW2b);
  bin_scanA_kernel<<<NBUK, 256, 0, stream>>>(counts, offl, btot);
  bin_scanB_kernel<<<1, 128, 0, stream>>>(btot, bb);
  bin_write_enc_kernel<<<B1C + NGRID64, 256, 0, stream>>>(
      ei, offl, bb, pairs,
      x, aW1, ab1, ag, abe, aW2, ab2,
      oW1, ob1, og, obe, oW2, ob2,
      ninWb, ninb, Ha);
  bucket_build_kernel<<<NBUK, 256, 0, stream>>>(pairs, bb, rowptr, esrc);

  // layer 1: Ha -> Hc ; layer 2: Hc -> Ha ; layer 3 (+gate): Ha -> Hc
  layer_kernel<false><<<NGRID64, 256, 0, stream>>>(
      Ha, rowptr, esrc, eps + 0,
      cW1b + 0*HIDC*HIDC, cb1 + 0*HIDC, cg + 0*HIDC, cbe + 0*HIDC,
      cW2b + 0*HIDC*HIDC, cb2 + 0*HIDC, lng + 0*HIDC, lnb + 0*HIDC,
      Hc,
      gW1, gb1, gg, gbe, gW2, gb2, batch, gateb, gmaxu);
  layer_kernel<false><<<NGRID64, 256, 0, stream>>>(
      Hc, rowptr, esrc, eps + 1,
      cW1b + 1*HIDC*HIDC, cb1 + 1*HIDC, cg + 1*HIDC, cbe + 1*HIDC,
      cW2b + 1*HIDC*HIDC, cb2 + 1*HIDC, lng + 1*HIDC, lnb + 1*HIDC,
      Ha,
      gW1, gb1, gg, gbe, gW2, gb2, batch, gateb, gmaxu);
  layer_kernel<true><<<NGRID64, 256, 0, stream>>>(
      Ha, rowptr, esrc, eps + 2,
      cW1b + 2*HIDC*HIDC, cb1 + 2*HIDC, cg + 2*HIDC, cbe + 2*HIDC,
      cW2b + 2*HIDC*HIDC, cb2 + 2*HIDC, lng + 2*HIDC, lnb + 2*HIDC,
      Hc,
      gW1, gb1, gg, gbe, gW2, gb2, batch, gateb, gmaxu);

  pool_kernel<<<N_GRAPHSC * POOL_SPLIT, 256, 0, stream>>>(Hc, gateb, gstart, gmaxu, S, denom);
  head_kernel<<<N_GRAPHSC, 64, 0, stream>>>(S, denom, hW1, hb1, hg, hbe, hW2, hb2,
                                            (float*)d_out);
}

// Round 6
// 327.678 us; speedup vs baseline: 1.1549x; 1.1549x over previous
//
#include <hip/hip_runtime.h>

#define N_NODESC 50000
#define N_EDGESC 640000
#define N_GRAPHSC 64
#define HIDC 128
#define LN_EPSF 1e-5f
#define NGRID64 ((N_NODESC + 63) / 64)
#define PREP_ELEMS (8192 + 49152 + 49152)   // ninWb + cW1b + cW2b
#define WPREP_NB ((PREP_ELEMS + 255) / 256) // 416
// ---- bucketed CSR build ----
#define B1C 200        // bin blocks
#define BCHUNK 3200    // edges per bin block (200*3200 = 640000 exactly)
#define NBUK 98        // ceil(50000/512)
#define WBUK 512       // nodes per bucket (dst>>9)

typedef short bf16x8 __attribute__((ext_vector_type(8)));
typedef float f32x4 __attribute__((ext_vector_type(4)));

// ---------- helpers ----------
static __device__ __forceinline__ unsigned short f2bf(float x) {
  unsigned u = __float_as_uint(x);
  u += 0x7fffu + ((u >> 16) & 1u);
  return (unsigned short)(u >> 16);
}
static __device__ __forceinline__ float bf2f(unsigned short b) {
  return __uint_as_float(((unsigned)b) << 16);
}

static __device__ __forceinline__ void mlp16(float in0, float in1, float in2,
    const float* __restrict__ W1, const float* __restrict__ b1,
    const float* __restrict__ g, const float* __restrict__ be,
    const float* __restrict__ W2, const float* __restrict__ b2,
    float* __restrict__ out) {
  float h[16];
  float s1 = 0.f, s2 = 0.f;
#pragma unroll
  for (int j = 0; j < 16; ++j) {
    float v = b1[j] + W1[j*3+0]*in0 + W1[j*3+1]*in1 + W1[j*3+2]*in2;
    v = fmaxf(v, 0.f);
    h[j] = v; s1 += v; s2 += v*v;
  }
  float mu = s1 * (1.f/16.f);
  float var = fmaxf(s2 * (1.f/16.f) - mu*mu, 0.f);
  float rs = rsqrtf(var + LN_EPSF);
  float z[16];
#pragma unroll
  for (int j = 0; j < 16; ++j) z[j] = (h[j]-mu)*rs*g[j] + be[j];
#pragma unroll
  for (int j = 0; j < 16; ++j) {
    float v = b2[j];
#pragma unroll
    for (int k = 0; k < 16; ++k) v += W2[j*16+k]*z[k];
    out[j] = v;
  }
}

// ---------- bin_count: bucket histogram (LDS atomics) + S/denom zero + weight prep ----------
__global__ __launch_bounds__(256) void bin_count_kernel(const int* __restrict__ ei,
    int* __restrict__ counts,
    float* __restrict__ Szero,   // S followed contiguously by denom (8256 floats)
    const float* __restrict__ ninW, unsigned short* __restrict__ ninWb,
    const float* __restrict__ cW1, unsigned short* __restrict__ cW1b,
    const float* __restrict__ cW2, unsigned short* __restrict__ cW2b) {
  const int b = blockIdx.x;
  if (b < B1C) {
    __shared__ int cnt[NBUK];
    for (int i = threadIdx.x; i < NBUK; i += 256) cnt[i] = 0;
    __syncthreads();
    const int e0 = b * BCHUNK;
    const int e1 = e0 + BCHUNK;
    for (int e = e0 + threadIdx.x; e < e1; e += 256)
      atomicAdd(&cnt[ei[N_EDGESC + e] >> 9], 1);
    __syncthreads();
    for (int i = threadIdx.x; i < NBUK; i += 256)
      counts[i * B1C + b] = cnt[i];
  } else if (b == B1C) {
    // zero S (64*128) + denom (64) = 8256 floats
    for (int i = threadIdx.x; i < N_GRAPHSC * HIDC + N_GRAPHSC; i += 256)
      Szero[i] = 0.f;
  } else {
    int i = (b - B1C - 1) * 256 + threadIdx.x;
    if (i < 8192) {
      int f = i >> 6, k = i & 63;
      ninWb[i] = (k < 45) ? f2bf(ninW[f*45 + k]) : (unsigned short)0;
    } else if (i < 8192 + 49152) {
      int j = i - 8192;
      cW1b[j] = f2bf(cW1[j]);
    } else if (i < PREP_ELEMS) {
      int j = i - 8192 - 49152;
      cW2b[j] = f2bf(cW2[j]);
    }
  }
}

// ---------- bin_scanA: per-bucket exclusive scan over the 200 block counts ----------
__global__ __launch_bounds__(256) void bin_scanA_kernel(const int* __restrict__ counts,
                                                        int* __restrict__ offl,
                                                        int* __restrict__ btot) {
  const int buk = blockIdx.x, t = threadIdx.x;
  const int lane = t & 63, w = t >> 6;
  int v = (t < B1C) ? counts[buk * B1C + t] : 0;
  const int orig = v;
#pragma unroll
  for (int off = 1; off < 64; off <<= 1) {
    int n = __shfl_up(v, off);
    if (lane >= off) v += n;
  }
  __shared__ int wsum[4];
  if (lane == 63) wsum[w] = v;
  __syncthreads();
  if (t == 0) {
    int run = 0;
#pragma unroll
    for (int k = 0; k < 4; ++k) { int x = wsum[k]; wsum[k] = run; run += x; }
  }
  __syncthreads();
  int incl = v + wsum[w];
  if (t < B1C) offl[buk * B1C + t] = incl - orig;
  if (t == 255) btot[buk] = incl;
}

// ---------- bin_scanB: scan bucket totals -> bucket bases ----------
__global__ __launch_bounds__(128) void bin_scanB_kernel(const int* __restrict__ btot,
                                                        int* __restrict__ bb) {
  const int t = threadIdx.x, lane = t & 63, w = t >> 6;
  int v = (t < NBUK) ? btot[t] : 0;
  const int orig = v;
#pragma unroll
  for (int off = 1; off < 64; off <<= 1) {
    int n = __shfl_up(v, off);
    if (lane >= off) v += n;
  }
  __shared__ int ws2[2];
  if (lane == 63) ws2[w] = v;
  __syncthreads();
  int add = (w == 1) ? ws2[0] : 0;
  int excl = v + add - orig;
  if (t < NBUK) bb[t] = excl;
  if (t == 0) bb[NBUK] = N_EDGESC;
}

// ---------- bin_write (LDS cursors, partition pairs by bucket) + encoder MFMA blocks ----------
__global__ __launch_bounds__(256, 4) void bin_write_enc_kernel(
    const int* __restrict__ ei, const int* __restrict__ offl, const int* __restrict__ bb,
    int2* __restrict__ pairs,
    const float* __restrict__ x,
    const float* __restrict__ aW1, const float* __restrict__ ab1,
    const float* __restrict__ ag,  const float* __restrict__ abe,
    const float* __restrict__ aW2, const float* __restrict__ ab2,
    const float* __restrict__ oW1, const float* __restrict__ ob1,
    const float* __restrict__ og,  const float* __restrict__ obe,
    const float* __restrict__ oW2, const float* __restrict__ ob2,
    const unsigned short* __restrict__ ninWb, const float* __restrict__ ninb,
    unsigned short* __restrict__ Hb) {
  __shared__ unsigned short Ab[64*136];
  const int t = threadIdx.x;

  if (blockIdx.x < B1C) {
    // ---- partition pass: LDS cursors, no global atomics ----
    int* cur = (int*)Ab;
    const int blk = blockIdx.x;
    for (int i = t; i < NBUK; i += 256) cur[i] = bb[i] + offl[i * B1C + blk];
    __syncthreads();
    const int e0 = blk * BCHUNK;
    const int e1 = e0 + BCHUNK;
    for (int e = e0 + t; e < e1; e += 256) {
      int s = ei[e], d = ei[N_EDGESC + e];
      int pos = atomicAdd(&cur[d >> 9], 1);
      pairs[pos] = make_int2(s, d);
    }
    return;
  }

  // ---- encoder part ----
  const int nb = (blockIdx.x - B1C) * 64;

  if (t < 192) {
    const int n = t & 63;
    const int gn = nb + n;
    const int grp = t >> 6;
    if (gn < N_NODESC) {
      const float* xr = x + gn * 19;
      if (grp == 0) {
        float z[16];
        mlp16(xr[9], xr[10], xr[11], aW1, ab1, ag, abe, aW2, ab2, z);
#pragma unroll
        for (int k = 0; k < 16; ++k) Ab[n*136 + 13 + k] = f2bf(z[k]);
      } else if (grp == 1) {
        float z[16];
        mlp16(xr[12], xr[13], xr[14], oW1, ob1, og, obe, oW2, ob2, z);
#pragma unroll
        for (int k = 0; k < 16; ++k) Ab[n*136 + 29 + k] = f2bf(z[k]);
      } else {
#pragma unroll
        for (int k = 0; k < 9; ++k) Ab[n*136 + k] = f2bf(xr[k]);
#pragma unroll
        for (int k = 0; k < 4; ++k) Ab[n*136 + 9 + k] = f2bf(xr[15 + k]);
#pragma unroll
        for (int k = 45; k < 64; ++k) Ab[n*136 + k] = 0;
      }
    } else {
      if (grp == 0) {
#pragma unroll
        for (int k = 0; k < 16; ++k) Ab[n*136 + 13 + k] = 0;
      } else if (grp == 1) {
#pragma unroll
        for (int k = 0; k < 16; ++k) Ab[n*136 + 29 + k] = 0;
      } else {
#pragma unroll
        for (int k = 0; k < 13; ++k) Ab[n*136 + k] = 0;
#pragma unroll
        for (int k = 45; k < 64; ++k) Ab[n*136 + k] = 0;
      }
    }
  }
  __syncthreads();

  const int lane = t & 63, wv = t >> 6;
  const int quad = lane >> 4, l16 = lane & 15;
  const int arow = (wv*16 + l16)*136 + quad*8;
  f32x4 acc[8];
#pragma unroll
  for (int ft = 0; ft < 8; ++ft) acc[ft] = (f32x4){0.f,0.f,0.f,0.f};
#pragma unroll
  for (int ks = 0; ks < 2; ++ks) {
    bf16x8 a = *(const bf16x8*)(const void*)&Ab[arow + ks*32];
#pragma unroll
    for (int ft = 0; ft < 8; ++ft) {
      bf16x8 bfr = *(const bf16x8*)&ninWb[(ft*16 + l16)*64 + quad*8 + ks*32];
      acc[ft] = __builtin_amdgcn_mfma_f32_16x16x32_bf16(a, bfr, acc[ft], 0, 0, 0);
    }
  }
  float bbv[8];
#pragma unroll
  for (int ft = 0; ft < 8; ++ft) bbv[ft] = ninb[ft*16 + l16];
  __syncthreads();
#pragma unroll
  for (int r = 0; r < 4; ++r) {
    int nloc = wv*16 + quad*4 + r;
#pragma unroll
    for (int ft = 0; ft < 8; ++ft)
      Ab[nloc*136 + ft*16 + l16] = f2bf(acc[ft][r] + bbv[ft]);
  }
  __syncthreads();
#pragma unroll
  for (int i = 0; i < 4; ++i) {
    int chunk = t + i*256;
    int n = chunk >> 4, c8 = chunk & 15;
    int gn = nb + n;
    if (gn < N_NODESC)
      *(bf16x8*)&Hb[gn*HIDC + c8*8] = *(const bf16x8*)&Ab[n*136 + c8*8];
  }
}

// ---------- bucket_build: per-bucket LDS hist -> scan -> rowptr + esrc scatter (LDS cursors) ----------
__global__ __launch_bounds__(256) void bucket_build_kernel(const int2* __restrict__ pairs,
    const int* __restrict__ bb, int* __restrict__ rowptr, int* __restrict__ esrc) {
  __shared__ int hist[WBUK];
  __shared__ int wsum[4];
  __shared__ int totS;
  const int b = blockIdx.x, t = threadIdx.x;
  const int lane = t & 63, w = t >> 6;
  const int node0 = b * WBUK;
  for (int i = t; i < WBUK; i += 256) hist[i] = 0;
  __syncthreads();
  const int base = bb[b], end = bb[b + 1];
  for (int p = base + t; p < end; p += 256)
    atomicAdd(&hist[pairs[p].y - node0], 1);
  __syncthreads();
  const int v0 = hist[t], v1 = hist[256 + t];
  // exclusive scan of hist[0..255]
  int a = v0;
#pragma unroll
  for (int off = 1; off < 64; off <<= 1) {
    int n = __shfl_up(a, off);
    if (lane >= off) a += n;
  }
  if (lane == 63) wsum[w] = a;
  __syncthreads();
  if (t == 0) {
    int run = 0;
#pragma unroll
    for (int k = 0; k < 4; ++k) { int x = wsum[k]; wsum[k] = run; run += x; }
    totS = run;
  }
  __syncthreads();
  const int e0 = a + wsum[w] - v0;
  const int tot0 = totS;
  __syncthreads();
  // exclusive scan of hist[256..511] (+ carry tot0)
  int c = v1;
#pragma unroll
  for (int off = 1; off < 64; off <<= 1) {
    int n = __shfl_up(c, off);
    if (lane >= off) c += n;
  }
  if (lane == 63) wsum[w] = c;
  __syncthreads();
  if (t == 0) {
    int run = 0;
#pragma unroll
    for (int k = 0; k < 4; ++k) { int x = wsum[k]; wsum[k] = run; run += x; }
  }
  __syncthreads();
  const int e1 = tot0 + c + wsum[w] - v1;
  // write rowptr, convert hist -> cursors
  hist[t] = e0;
  hist[256 + t] = e1;
  const int n0 = node0 + t, n1 = node0 + 256 + t;
  if (n0 < N_NODESC) rowptr[n0] = base + e0;
  if (n1 < N_NODESC) rowptr[n1] = base + e1;
  __syncthreads();
  for (int p = base + t; p < end; p += 256) {
    int2 pr = pairs[p];
    int slot = base + atomicAdd(&hist[pr.y - node0], 1);
    esrc[slot] = pr.x;
  }
  if (b == NBUK - 1 && t == 0) rowptr[N_NODESC] = N_EDGESC;
}

// ---------- aggregation (bf16, standalone for max gather parallelism) ----------
__global__ __launch_bounds__(128) void agg_kernel(const unsigned short* __restrict__ Hb,
    const int* __restrict__ rowptr, const int* __restrict__ esrc,
    const float* __restrict__ epsp, unsigned short* __restrict__ Mb) {
  const int t = threadIdx.x;
  const int c8 = t & 15;
  const int v  = t >> 4;
  const int node = blockIdx.x * 8 + v;
  if (node >= N_NODESC) return;
  const float e1 = 1.0f + epsp[0];
  bf16x8 h = *(const bf16x8*)&Hb[node*HIDC + c8*8];
  float acc[8];
#pragma unroll
  for (int k = 0; k < 8; ++k) acc[k] = 0.f;
  int s = rowptr[node];
  const int e = rowptr[node+1];
  for (; s + 8 <= e; s += 8) {
    int i0 = esrc[s],   i1 = esrc[s+1], i2 = esrc[s+2], i3 = esrc[s+3];
    int i4 = esrc[s+4], i5 = esrc[s+5], i6 = esrc[s+6], i7 = esrc[s+7];
    bf16x8 x0 = *(const bf16x8*)&Hb[i0*HIDC + c8*8];
    bf16x8 x1 = *(const bf16x8*)&Hb[i1*HIDC + c8*8];
    bf16x8 x2 = *(const bf16x8*)&Hb[i2*HIDC + c8*8];
    bf16x8 x3 = *(const bf16x8*)&Hb[i3*HIDC + c8*8];
    bf16x8 x4 = *(const bf16x8*)&Hb[i4*HIDC + c8*8];
    bf16x8 x5 = *(const bf16x8*)&Hb[i5*HIDC + c8*8];
    bf16x8 x6 = *(const bf16x8*)&Hb[i6*HIDC + c8*8];
    bf16x8 x7 = *(const bf16x8*)&Hb[i7*HIDC + c8*8];
#pragma unroll
    for (int k = 0; k < 8; ++k)
      acc[k] += ((bf2f((unsigned short)x0[k]) + bf2f((unsigned short)x1[k]))
               + (bf2f((unsigned short)x2[k]) + bf2f((unsigned short)x3[k])))
              + ((bf2f((unsigned short)x4[k]) + bf2f((unsigned short)x5[k]))
               + (bf2f((unsigned short)x6[k]) + bf2f((unsigned short)x7[k])));
  }
  for (; s + 4 <= e; s += 4) {
    int i0 = esrc[s], i1 = esrc[s+1], i2 = esrc[s+2], i3 = esrc[s+3];
    bf16x8 x0 = *(const bf16x8*)&Hb[i0*HIDC + c8*8];
    bf16x8 x1 = *(const bf16x8*)&Hb[i1*HIDC + c8*8];
    bf16x8 x2 = *(const bf16x8*)&Hb[i2*HIDC + c8*8];
    bf16x8 x3 = *(const bf16x8*)&Hb[i3*HIDC + c8*8];
#pragma unroll
    for (int k = 0; k < 8; ++k)
      acc[k] += (bf2f((unsigned short)x0[k]) + bf2f((unsigned short)x1[k]))
              + (bf2f((unsigned short)x2[k]) + bf2f((unsigned short)x3[k]));
  }
  for (; s < e; ++s) {
    bf16x8 x0 = *(const bf16x8*)&Hb[esrc[s]*HIDC + c8*8];
#pragma unroll
    for (int k = 0; k < 8; ++k) acc[k] += bf2f((unsigned short)x0[k]);
  }
  bf16x8 m8;
#pragma unroll
  for (int k = 0; k < 8; ++k)
    m8[k] = (short)f2bf(e1*bf2f((unsigned short)h[k]) + acc[k]);
  *(bf16x8*)&Mb[node*HIDC + c8*8] = m8;
}

// ---------- GEMM pair: T = LN(relu(M@W1^T+b1)); H' = LN(relu(T@W2^T+b2)) + Hin ----------
// When GATE: gate MLP on the final H tile (still in LDS) + DIRECT softmax-pooling
// accumulation into S/denom (no max subtraction: attn = e/denom is scale-invariant;
// LN-bounded gates keep exp() safely in f32 range). pool_kernel eliminated.
template<bool GATE>
__global__ __launch_bounds__(256, 3) void gemmpair_kernel(
    const unsigned short* __restrict__ Mb,
    const unsigned short* __restrict__ Hin,
    const unsigned short* __restrict__ W1b, const float* __restrict__ b1,
    const float* __restrict__ g1, const float* __restrict__ be1,
    const unsigned short* __restrict__ W2b, const float* __restrict__ b2,
    const float* __restrict__ lng, const float* __restrict__ lnb,
    unsigned short* __restrict__ Hout,
    const float* __restrict__ gW1, const float* __restrict__ gb1,
    const float* __restrict__ glng, const float* __restrict__ glnb,
    const float* __restrict__ gW2, const float* __restrict__ gb2,
    const int* __restrict__ batch, float* __restrict__ S,
    float* __restrict__ denom) {
  __shared__ unsigned short Ab[64*136];   // M tile -> T tile -> OUT tile -> (H tile)
  __shared__ unsigned short Wl[128*136];  // W1 then W2 (then gate W1)
  __shared__ float Egate[64];
  __shared__ int   Sbatch[64];
  const int t = threadIdx.x;
  const int nb = blockIdx.x * 64;

  // stage A tile from Mb
#pragma unroll
  for (int i = 0; i < 4; ++i) {
    int chunk = t + i*256;
    int n = chunk >> 4, c8 = chunk & 15;
    int gn = nb + n;
    bf16x8 v = {0,0,0,0,0,0,0,0};
    if (gn < N_NODESC) v = *(const bf16x8*)&Mb[gn*HIDC + c8*8];
    *(bf16x8*)&Ab[n*136 + c8*8] = v;
  }
  // stage W1 (bf16 straight copy, 16B chunks)
#pragma unroll
  for (int i = 0; i < 8; ++i) {
    int q = t + i*256;
    int f = q >> 4, c8 = q & 15;
    *(bf16x8*)&Wl[f*136 + c8*8] = *(const bf16x8*)&W1b[f*HIDC + c8*8];
  }
  __syncthreads();

  const int lane = t & 63, wv = t >> 6;
  const int quad = lane >> 4, l16 = lane & 15;
  const int arow = (wv*16 + l16)*136 + quad*8;

  // MFMA loop 1
  f32x4 acc[8];
#pragma unroll
  for (int ft = 0; ft < 8; ++ft) acc[ft] = (f32x4){0.f,0.f,0.f,0.f};
#pragma unroll
  for (int ks = 0; ks < 4; ++ks) {
    bf16x8 a = *(const bf16x8*)(const void*)&Ab[arow + ks*32];
#pragma unroll
    for (int ft = 0; ft < 8; ++ft) {
      bf16x8 b = *(const bf16x8*)(const void*)&Wl[(ft*16 + l16)*136 + quad*8 + ks*32];
      acc[ft] = __builtin_amdgcn_mfma_f32_16x16x32_bf16(a, b, acc[ft], 0, 0, 0);
    }
  }

  // epilogue 1: bias + relu + LN -> T in Ab
  {
    float bbv[8], gg[8], bee[8];
#pragma unroll
    for (int ft = 0; ft < 8; ++ft) {
      int f = ft*16 + l16;
      bbv[ft] = b1[f]; gg[ft] = g1[f]; bee[ft] = be1[f];
    }
    float s1[4] = {0,0,0,0}, s2[4] = {0,0,0,0};
#pragma unroll
    for (int ft = 0; ft < 8; ++ft)
#pragma unroll
      for (int r = 0; r < 4; ++r) {
        float v = fmaxf(acc[ft][r] + bbv[ft], 0.f);
        acc[ft][r] = v; s1[r] += v; s2[r] += v*v;
      }
#pragma unroll
    for (int m = 1; m < 16; m <<= 1)
#pragma unroll
      for (int r = 0; r < 4; ++r) {
        s1[r] += __shfl_xor(s1[r], m);
        s2[r] += __shfl_xor(s2[r], m);
      }
    float mu[4], rs[4];
#pragma unroll
    for (int r = 0; r < 4; ++r) {
      mu[r] = s1[r] * (1.f/128.f);
      float var = fmaxf(s2[r] * (1.f/128.f) - mu[r]*mu[r], 0.f);
      rs[r] = rsqrtf(var + LN_EPSF);
    }
    __syncthreads();
#pragma unroll
    for (int r = 0; r < 4; ++r) {
      int nloc = wv*16 + quad*4 + r;
#pragma unroll
      for (int ft = 0; ft < 8; ++ft) {
        float o = (acc[ft][r] - mu[r])*rs[r]*gg[ft] + bee[ft];
        Ab[nloc*136 + ft*16 + l16] = f2bf(o);
      }
    }
  }
  // restage Wl = W2 (bf16)
#pragma unroll
  for (int i = 0; i < 8; ++i) {
    int q = t + i*256;
    int f = q >> 4, c8 = q & 15;
    *(bf16x8*)&Wl[f*136 + c8*8] = *(const bf16x8*)&W2b[f*HIDC + c8*8];
  }
  __syncthreads();

  // MFMA loop 2
#pragma unroll
  for (int ft = 0; ft < 8; ++ft) acc[ft] = (f32x4){0.f,0.f,0.f,0.f};
#pragma unroll
  for (int ks = 0; ks < 4; ++ks) {
    bf16x8 a = *(const bf16x8*)(const void*)&Ab[arow + ks*32];
#pragma unroll
    for (int ft = 0; ft < 8; ++ft) {
      bf16x8 b = *(const bf16x8*)(const void*)&Wl[(ft*16 + l16)*136 + quad*8 + ks*32];
      acc[ft] = __builtin_amdgcn_mfma_f32_16x16x32_bf16(a, b, acc[ft], 0, 0, 0);
    }
  }

  // epilogue 2: bias + relu + LN -> Ab
  {
    float bbv[8], gg[8], bee[8];
#pragma unroll
    for (int ft = 0; ft < 8; ++ft) {
      int f = ft*16 + l16;
      bbv[ft] = b2[f]; gg[ft] = lng[f]; bee[ft] = lnb[f];
    }
    float s1[4] = {0,0,0,0}, s2[4] = {0,0,0,0};
#pragma unroll
    for (int ft = 0; ft < 8; ++ft)
#pragma unroll
      for (int r = 0; r < 4; ++r) {
        float v = fmaxf(acc[ft][r] + bbv[ft], 0.f);
        acc[ft][r] = v; s1[r] += v; s2[r] += v*v;
      }
#pragma unroll
    for (int m = 1; m < 16; m <<= 1)
#pragma unroll
      for (int r = 0; r < 4; ++r) {
        s1[r] += __shfl_xor(s1[r], m);
        s2[r] += __shfl_xor(s2[r], m);
      }
    float mu[4], rs[4];
#pragma unroll
    for (int r = 0; r < 4; ++r) {
      mu[r] = s1[r] * (1.f/128.f);
      float var = fmaxf(s2[r] * (1.f/128.f) - mu[r]*mu[r], 0.f);
      rs[r] = rsqrtf(var + LN_EPSF);
    }
    __syncthreads();
#pragma unroll
    for (int r = 0; r < 4; ++r) {
      int nloc = wv*16 + quad*4 + r;
#pragma unroll
      for (int ft = 0; ft < 8; ++ft) {
        float o = (acc[ft][r] - mu[r])*rs[r]*gg[ft] + bee[ft];
        Ab[nloc*136 + ft*16 + l16] = f2bf(o);
      }
    }
  }
  __syncthreads();
  // final store: + residual (Hin row), coalesced 16B chunks.
  // When GATE, also keep final H in Ab (same thread owns read+write slot).
#pragma unroll
  for (int i = 0; i < 4; ++i) {
    int chunk = t + i*256;
    int n = chunk >> 4, cc = chunk & 15;
    int gn = nb + n;
    bf16x8 o8 = {0,0,0,0,0,0,0,0};
    if (gn < N_NODESC) {
      bf16x8 vv = *(const bf16x8*)&Ab[n*136 + cc*8];
      bf16x8 rr = *(const bf16x8*)&Hin[gn*HIDC + cc*8];
#pragma unroll
      for (int k = 0; k < 8; ++k)
        o8[k] = (short)f2bf(bf2f((unsigned short)vv[k]) + bf2f((unsigned short)rr[k]));
      *(bf16x8*)&Hout[gn*HIDC + cc*8] = o8;
    }
    if (GATE) *(bf16x8*)&Ab[n*136 + cc*8] = o8;
  }

  if (GATE) {
    // stage gate W1 (f32 -> bf16) into Wl (Wl's last read was before epilogue-2 barrier)
#pragma unroll
    for (int i = 0; i < 8; ++i) {
      int q = t + i*256;
      int f = q >> 5, c4 = q & 31;
      float4 v = *(const float4*)&gW1[f*HIDC + c4*4];
      ushort4 hh;
      hh.x = f2bf(v.x); hh.y = f2bf(v.y); hh.z = f2bf(v.z); hh.w = f2bf(v.w);
      *(ushort4*)&Wl[f*136 + c4*4] = hh;
    }
    __syncthreads();   // orders Ab final-H writes and Wl gate-W writes

    f32x4 gacc[4];
#pragma unroll
    for (int ft = 0; ft < 4; ++ft) gacc[ft] = (f32x4){0.f,0.f,0.f,0.f};
#pragma unroll
    for (int ks = 0; ks < 4; ++ks) {
      bf16x8 a = *(const bf16x8*)(const void*)&Ab[arow + ks*32];
#pragma unroll
      for (int ft = 0; ft < 4; ++ft) {
        bf16x8 b = *(const bf16x8*)(const void*)&Wl[(ft*16 + l16)*136 + quad*8 + ks*32];
        gacc[ft] = __builtin_amdgcn_mfma_f32_16x16x32_bf16(a, b, gacc[ft], 0, 0, 0);
      }
    }

    float bbv[4], gg[4], bee[4], w2v[4];
#pragma unroll
    for (int ft = 0; ft < 4; ++ft) {
      int f = ft*16 + l16;
      bbv[ft] = gb1[f]; gg[ft] = glng[f]; bee[ft] = glnb[f]; w2v[ft] = gW2[f];
    }
    float s1[4] = {0,0,0,0}, s2[4] = {0,0,0,0};
#pragma unroll
    for (int ft = 0; ft < 4; ++ft)
#pragma unroll
      for (int r = 0; r < 4; ++r) {
        float v = fmaxf(gacc[ft][r] + bbv[ft], 0.f);
        gacc[ft][r] = v; s1[r] += v; s2[r] += v*v;
      }
#pragma unroll
    for (int m = 1; m < 16; m <<= 1)
#pragma unroll
      for (int r = 0; r < 4; ++r) {
        s1[r] += __shfl_xor(s1[r], m);
        s2[r] += __shfl_xor(s2[r], m);
      }
    float pd[4];
#pragma unroll
    for (int r = 0; r < 4; ++r) {
      float mu = s1[r] * (1.f/64.f);
      float var = fmaxf(s2[r] * (1.f/64.f) - mu*mu, 0.f);
      float rs = rsqrtf(var + LN_EPSF);
      float p = 0.f;
#pragma unroll
      for (int ft = 0; ft < 4; ++ft)
        p += ((gacc[ft][r] - mu)*rs*gg[ft] + bee[ft]) * w2v[ft];
      pd[r] = p;
    }
#pragma unroll
    for (int m = 1; m < 16; m <<= 1)
#pragma unroll
      for (int r = 0; r < 4; ++r) pd[r] += __shfl_xor(pd[r], m);
    if (l16 == 0) {
      float b2v = gb2[0];
#pragma unroll
      for (int r = 0; r < 4; ++r) {
        int nloc = wv*16 + quad*4 + r;
        int node = nb + nloc;
        if (node < N_NODESC) {
          Egate[nloc]  = expf(pd[r] + b2v);
          Sbatch[nloc] = batch[node];
        } else {
          Egate[nloc]  = 0.f;
          Sbatch[nloc] = -1;
        }
      }
    }
    __syncthreads();

    // segmented softmax-pool accumulation: S[g][f] += sum E*h ; denom[g] += sum E
    if (t < HIDC) {
      const int f = t;
      float accS = 0.f;
      int curG = Sbatch[0];
#pragma unroll 4
      for (int n = 0; n < 64; ++n) {
        int g = Sbatch[n];
        if (g != curG) {
          if (curG >= 0) atomicAdd(&S[curG*HIDC + f], accS);
          accS = 0.f; curG = g;
        }
        if (g >= 0) accS += Egate[n] * bf2f((unsigned short)Ab[n*136 + f]);
      }
      if (curG >= 0) atomicAdd(&S[curG*HIDC + f], accS);
    } else if (t == HIDC) {
      float accD = 0.f;
      int curG = Sbatch[0];
      for (int n = 0; n < 64; ++n) {
        int g = Sbatch[n];
        if (g != curG) {
          if (curG >= 0) atomicAdd(&denom[curG], accD);
          accD = 0.f; curG = g;
        }
        if (g >= 0) accD += Egate[n];
      }
      if (curG >= 0) atomicAdd(&denom[curG], accD);
    }
  }
}

// ---------- head MLP per graph ----------
__global__ __launch_bounds__(64) void head_kernel(const float* __restrict__ S,
    const float* __restrict__ denom, const float* __restrict__ W1,
    const float* __restrict__ b1, const float* __restrict__ g,
    const float* __restrict__ be, const float* __restrict__ W2,
    const float* __restrict__ b2, float* __restrict__ out) {
  const int gr = blockIdx.x;
  const int j = threadIdx.x;
  const float inv = 1.0f / denom[gr];
  float v = b1[j];
  for (int k = 0; k < HIDC; ++k) v += (S[gr*HIDC + k] * inv) * W1[j*HIDC + k];
  v = fmaxf(v, 0.f);
  float s1 = v, s2 = v*v;
  for (int off = 32; off; off >>= 1) { s1 += __shfl_xor(s1, off); s2 += __shfl_xor(s2, off); }
  float mu = s1 * (1.f/64.f);
  float var = fmaxf(s2 * (1.f/64.f) - mu*mu, 0.f);
  float rs = rsqrtf(var + LN_EPSF);
  float z = (v-mu)*rs*g[j] + be[j];
  float p = z * W2[j];
  for (int off = 32; off; off >>= 1) p += __shfl_xor(p, off);
  if (j == 0) out[gr] = p + b2[0];
}

// ---------- launch ----------
extern "C" void kernel_launch(void* const* d_in, const int* in_sizes, int n_in,
                              void* d_out, int out_size, void* d_ws, size_t ws_size,
                              hipStream_t stream) {
  (void)in_sizes; (void)n_in; (void)out_size; (void)ws_size;
  const float* x     = (const float*)d_in[0];
  const int*   ei    = (const int*)d_in[1];
  const int*   batch = (const int*)d_in[2];
  const float* aW1 = (const float*)d_in[3];
  const float* ab1 = (const float*)d_in[4];
  const float* ag  = (const float*)d_in[5];
  const float* abe = (const float*)d_in[6];
  const float* aW2 = (const float*)d_in[7];
  const float* ab2 = (const float*)d_in[8];
  const float* oW1 = (const float*)d_in[9];
  const float* ob1 = (const float*)d_in[10];
  const float* og  = (const float*)d_in[11];
  const float* obe = (const float*)d_in[12];
  const float* oW2 = (const float*)d_in[13];
  const float* ob2 = (const float*)d_in[14];
  const float* ninW = (const float*)d_in[15];
  const float* ninb = (const float*)d_in[16];
  const float* cW1 = (const float*)d_in[17];
  const float* cb1 = (const float*)d_in[18];
  const float* cg  = (const float*)d_in[19];
  const float* cbe = (const float*)d_in[20];
  const float* cW2 = (const float*)d_in[21];
  const float* cb2 = (const float*)d_in[22];
  const float* eps = (const float*)d_in[23];
  const float* lng = (const float*)d_in[24];
  const float* lnb = (const float*)d_in[25];
  const float* gW1 = (const float*)d_in[26];
  const float* gb1 = (const float*)d_in[27];
  const float* gg  = (const float*)d_in[28];
  const float* gbe = (const float*)d_in[29];
  const float* gW2 = (const float*)d_in[30];
  const float* gb2 = (const float*)d_in[31];
  const float* hW1 = (const float*)d_in[32];
  const float* hb1 = (const float*)d_in[33];
  const float* hg  = (const float*)d_in[34];
  const float* hbe = (const float*)d_in[35];
  const float* hW2 = (const float*)d_in[36];
  const float* hb2 = (const float*)d_in[37];

  char* ws = (char*)d_ws;
  unsigned short* Ha = (unsigned short*)(ws + 0);          // 12,800,000 B
  unsigned short* Hc = (unsigned short*)(ws + 12800000);   // 12,800,000 B
  unsigned short* Mb = (unsigned short*)(ws + 25600000);   // 12,800,000 B
  // CSR-build scratch aliases the Mb region (dead before first agg writes Mb):
  int2* pairs  = (int2*)(ws + 25600000);                   // 640000*8 = 5,120,000 B
  int* counts  = (int*)(ws + 30720000);                    // 98*200*4 = 78,400 B
  int* offl    = (int*)(ws + 30800000);                    // 78,400 B
  int* btot    = (int*)(ws + 30880000);                    // 392 B
  int* bb      = (int*)(ws + 30881024);                    // 99*4 = 396 B
  // --- contiguous zero region: S | denom (zeroed by bin_count) ---
  float* S     = (float*)(ws + 38800000);                  // 32,768 B
  float* denom = (float*)(ws + 38832768);                  // 256 B
  // ----------------------------------------------------------------
  int* rowptr  = (int*)(ws + 38833280);                    // 200,004 B
  int* esrc    = (int*)(ws + 39233284);                    // 2,560,000 B
  unsigned short* ninWb = (unsigned short*)(ws + 41800000);// 16,384 B
  unsigned short* cW1b  = (unsigned short*)(ws + 41816384);// 98,304 B
  unsigned short* cW2b  = (unsigned short*)(ws + 41914688);// 98,304 B

  bin_count_kernel<<<B1C + 1 + WPREP_NB, 256, 0, stream>>>(
      ei, counts, S, ninW, ninWb, cW1, cW1b, cW2, cW2b);
  bin_scanA_kernel<<<NBUK, 256, 0, stream>>>(counts, offl, btot);
  bin_scanB_kernel<<<1, 128, 0, stream>>>(btot, bb);
  bin_write_enc_kernel<<<B1C + NGRID64, 256, 0, stream>>>(
      ei, offl, bb, pairs,
      x, aW1, ab1, ag, abe, aW2, ab2,
      oW1, ob1, og, obe, oW2, ob2,
      ninWb, ninb, Ha);
  bucket_build_kernel<<<NBUK, 256, 0, stream>>>(pairs, bb, rowptr, esrc);

  // layer 1: Ha -> Hc ; layer 2: Hc -> Ha ; layer 3 (+gate+pool): Ha -> Hc
  unsigned short* cur = Ha;
  unsigned short* nxt = Hc;
  for (int l = 0; l < 3; ++l) {
    agg_kernel<<<(N_NODESC + 7) / 8, 128, 0, stream>>>(cur, rowptr, esrc, eps + l, Mb);
    if (l < 2) {
      gemmpair_kernel<false><<<NGRID64, 256, 0, stream>>>(
          Mb, cur,
          cW1b + l*HIDC*HIDC, cb1 + l*HIDC, cg + l*HIDC, cbe + l*HIDC,
          cW2b + l*HIDC*HIDC, cb2 + l*HIDC, lng + l*HIDC, lnb + l*HIDC,
          nxt,
          gW1, gb1, gg, gbe, gW2, gb2, batch, S, denom);
    } else {
      gemmpair_kernel<true><<<NGRID64, 256, 0, stream>>>(
          Mb, cur,
          cW1b + l*HIDC*HIDC, cb1 + l*HIDC, cg + l*HIDC, cbe + l*HIDC,
          cW2b + l*HIDC*HIDC, cb2 + l*HIDC, lng + l*HIDC, lnb + l*HIDC,
          nxt,
          gW1, gb1, gg, gbe, gW2, gb2, batch, S, denom);
    }
    unsigned short* tmp = cur; cur = nxt; nxt = tmp;
  }

  head_kernel<<<N_GRAPHSC, 64, 0, stream>>>(S, denom, hW1, hb1, hg, hbe, hW2, hb2,
                                            (float*)d_out);
}